// Round 15
// baseline (167.965 us; speedup 1.0000x reference)
//
#include <hip/hip_runtime.h>
#include <hip/hip_bf16.h>
#include <cstdint>
#include <cstddef>

typedef __attribute__((ext_vector_type(8))) short short8;
typedef __attribute__((ext_vector_type(4))) float f32x4;

static constexpr int M_TOT = 31744;
static constexpr int N_TOT = 1152;
static constexpr int K_TOT = 768;
static constexpr long A_ELEMS = (long)M_TOT * K_TOT;   // 24379392
static constexpr long W_ELEMS = (long)N_TOT * K_TOT;   // 884736
static constexpr int CYC_ROWS = 3968;                  // one ragged cycle (4 images)

__device__ __forceinline__ unsigned short f2bf(float f) {
  unsigned int u = __float_as_uint(f);
  u += 0x7FFFu + ((u >> 16) & 1u);   // round-to-nearest-even
  return (unsigned short)(u >> 16);
}
__device__ __forceinline__ float bf2f(unsigned short u) {
  return __uint_as_float((unsigned int)u << 16);
}

// ---------------- pass 1: fp32 -> bf16 for A (seq_patches) and W ----------------
__global__ void cvt_kernel(const float* __restrict__ A, const float* __restrict__ W,
                           unsigned short* __restrict__ dst) {
  long chunk = (long)blockIdx.x * blockDim.x + threadIdx.x;  // one chunk = 8 floats
  long i = chunk * 8;
  const float* src = (i < A_ELEMS) ? (A + i) : (W + (i - A_ELEMS));
  float4 v0 = *(const float4*)(src);
  float4 v1 = *(const float4*)(src + 4);
  short8 o;
  o[0] = (short)f2bf(v0.x); o[1] = (short)f2bf(v0.y);
  o[2] = (short)f2bf(v0.z); o[3] = (short)f2bf(v0.w);
  o[4] = (short)f2bf(v1.x); o[5] = (short)f2bf(v1.y);
  o[6] = (short)f2bf(v1.z); o[7] = (short)f2bf(v1.w);
  *(short8*)(dst + i) = o;
}

// ---------------- pass 1b: pos table  tab[rem,d] = bf16(bias[d] + bilinear(pos)[rem,d]) ----
__global__ void tab_kernel(const float* __restrict__ pos, const float* __restrict__ bias,
                           unsigned short* __restrict__ tab) {
  const int t = blockIdx.x * blockDim.x + threadIdx.x;   // 571392 = 3968 * 144
  const int row = t / 144;
  const int dc = (t - row * 144) * 8;

  int rr, cc; float sy, sx;
  if (row < 1024)      { rr = row >> 5; cc = row & 31; sy = 0.5f;         sx = 0.5f; }
  else if (row < 2048) { const int li = row - 1024; rr = li >> 6; cc = li & 63; sy = 1.0f; sx = 0.25f; }
  else if (row < 3008) { const int li = row - 2048; rr = li / 40; cc = li - rr * 40; sy = 16.0f / 24.0f; sx = 0.4f; }
  else                 { const int li = row - 3008; rr = li / 24; cc = li - rr * 24; sy = 0.4f; sx = 16.0f / 24.0f; }
  float yc = fminf(fmaxf(((float)rr + 0.5f) * sy - 0.5f, 0.0f), 15.0f);
  const int y0 = (int)yc; const float fy = yc - (float)y0;
  const int y1 = y0 < 15 ? y0 + 1 : 15;
  float xc = fminf(fmaxf(((float)cc + 0.5f) * sx - 0.5f, 0.0f), 15.0f);
  const int x0 = (int)xc; const float fx = xc - (float)x0;
  const int x1 = x0 < 15 ? x0 + 1 : 15;
  const float w11 = fy * fx;
  const float w10 = fy - w11;
  const float w01 = fx - w11;
  const float w00 = 1.0f - fy - fx + w11;
  const float* p00 = pos + (size_t)(y0 * 16 + x0) * 1152 + dc;
  const float* p01 = pos + (size_t)(y0 * 16 + x1) * 1152 + dc;
  const float* p10 = pos + (size_t)(y1 * 16 + x0) * 1152 + dc;
  const float* p11 = pos + (size_t)(y1 * 16 + x1) * 1152 + dc;
  const float* bi  = bias + dc;
  short8 o;
#pragma unroll
  for (int j = 0; j < 8; ++j) {
    const float v = bi[j] + w00 * p00[j] + w01 * p01[j] + w10 * p10[j] + w11 * p11[j];
    o[j] = (short)f2bf(v);
  }
  *(short8*)(tab + (size_t)row * 1152 + dc) = o;
}

__device__ __forceinline__ void gload_lds16(const void* g, void* l) {
  __builtin_amdgcn_global_load_lds((__attribute__((address_space(1))) void*)g,
                                   (__attribute__((address_space(3))) void*)l, 16, 0, 0);
}

// ---------------- pass 2: r7 rhythm, A-only LDS (quad-buffer), B direct-to-regs ----
// 128x128 tile, BK=32, 24 K-steps, 256 threads = 4 waves (2x2), wave-tile 64x64.
// B fragments live in double-buffered REGISTERS (fbtA/fbtB), loaded from the
// L2-hot 1.77 MB W one iteration ahead (fixes r9's zero-prefetch confound).
// A: quad-buffered LDS 4 x 8 KB = 32 KB, gload_lds, prefetch depth 3.
// Ledger (issue order per iter: 4 B-reg then 2 A-gload):
//   steady wait vmcnt(8) leaves {A(t+2)2, B(t+1)4, A(t+3)2}; retires A(t) at
//   age 3 (and A(t+1) at age 2, both > HBM 900cy) and B(t) at age 1 (> L2 400cy).
//   Tail: vmcnt(6) @t=21, (4) @t=22, (0) @t=23.
// LDS traffic per block-step halves vs r7 (48 -> 24 KB).
__global__ __launch_bounds__(256, 3) void gemm_kernel(
    const unsigned short* __restrict__ Abf, const unsigned short* __restrict__ Wbf,
    const unsigned short* __restrict__ tab, float* __restrict__ outp) {
  __shared__ __attribute__((aligned(16))) unsigned short As[4][128 * 32];  // 4 x 8 KB

  // XCD-bijective swizzle: 2232 tiles = 8 XCDs * 279 (proven).
  const int bid = blockIdx.x;
  const int tile = (bid & 7) * 279 + (bid >> 3);
  const int tm = tile / 9, tn = tile % 9;   // 248 x 9 tiles of 128x128
  const int m0 = tm * 128, n0 = tn * 128;

  const int tid = threadIdx.x;
  const int wid = tid >> 6, lane = tid & 63;
  const int wr = wid >> 1, wc = wid & 1;    // 2x2 waves, 64x64 each
  const int kg = lane >> 4, l15 = lane & 15;

  // A staging (r7-proven map): row = base + (lane>>2), chunk = lane&3,
  // source chunk pre-swizzled by key (row>>1)&3 = (lane>>3)&3.
  const int srow = lane >> 2;
  const int schunk = ((lane & 3) ^ ((lane >> 3) & 3)) * 8;
  const unsigned short* Abase = Abf + (size_t)(m0 + wid * 16 + srow) * K_TOT + schunk;
  const int wu = wid << 10;                 // wave-uniform LDS byte base

  // B fragment base (MFMA layout direct from global W rows)
  const unsigned short* Bfrag = Wbf + (size_t)(n0 + wc * 64 + l15) * K_TOT + kg * 8;

  const int rkey = (l15 >> 1) & 3;          // ds_read swizzle key (r7-proven)

  f32x4 acc[4][4] = {};
  short8 fbtA[4], fbtB[4];                  // double-buffered B frags (static idx)

#define BLOAD(dst_, kt)                                                          \
  _Pragma("unroll") for (int n = 0; n < 4; ++n)                                  \
    dst_[n] = *(const short8*)(Bfrag + (size_t)(n * 16) * K_TOT + (kt) * 32);

#define STAGE_A(p_, kt)                                                          \
  { const int k0_ = (kt) * 32;                                                   \
    gload_lds16(Abase + k0_,                      (char*)As[p_] + wu);           \
    gload_lds16(Abase + (size_t)64 * K_TOT + k0_, (char*)As[p_] + 4096 + wu); }

#define COMPUTE(p_, fb_)                                                         \
  { __builtin_amdgcn_s_setprio(1);                                               \
    short8 fa[4];                                                                \
    _Pragma("unroll") for (int m = 0; m < 4; ++m) {                              \
      const int ar_ = wr * 64 + m * 16 + l15;                                    \
      fa[m] = *(const short8*)((const char*)As[p_] + ar_ * 64 +                  \
                               ((kg ^ rkey) << 4));                              \
    }                                                                            \
    _Pragma("unroll") for (int m = 0; m < 4; ++m)                                \
      _Pragma("unroll") for (int n = 0; n < 4; ++n)                              \
        acc[m][n] = __builtin_amdgcn_mfma_f32_16x16x32_bf16(                     \
            fa[m], fb_[n], acc[m][n], 0, 0, 0);                                  \
    __builtin_amdgcn_s_setprio(0); }

  // prologue: B(0) regs; A(0),A(1),A(2) staged (depth 3)
  BLOAD(fbtA, 0)
  STAGE_A(0, 0)
  STAGE_A(1, 1)
  STAGE_A(2, 2)
  // outstanding: B0(4), A0(2), A1(2), A2(2).  Retire B0+A0 -> vmcnt(4).
  asm volatile("s_waitcnt vmcnt(4)" ::: "memory");
  __builtin_amdgcn_s_barrier();

#pragma unroll
  for (int t = 0; t < 24; ++t) {
    const int p = t & 3;
    // B(t+1) first (so B(t)'s retire never drains younger A loads)
    if (t < 23) {
      if (t & 1) { BLOAD(fbtA, t + 1) } else { BLOAD(fbtB, t + 1) }
    }
    if (t < 21) STAGE_A((t + 3) & 3, t + 3)
    if (t > 0) {   // t=0 already waited in prologue-adjusted form below
      if (t < 21)       { asm volatile("s_waitcnt vmcnt(8)" ::: "memory"); }
      else if (t == 21) { asm volatile("s_waitcnt vmcnt(6)" ::: "memory"); }
      else if (t == 22) { asm volatile("s_waitcnt vmcnt(4)" ::: "memory"); }
      else              { asm volatile("s_waitcnt vmcnt(0)" ::: "memory"); }
      __builtin_amdgcn_s_barrier();   // As[p] resident for all waves
    }
    if (t & 1) { COMPUTE(p, fbtB) } else { COMPUTE(p, fbtA) }
    __builtin_amdgcn_s_barrier();     // nobody re-stages buf p until all read it
  }

#undef BLOAD
#undef STAGE_A
#undef COMPUTE

  // ---------------- epilogue (r5/r7-verified): out = acc + tab[s % 3968, d] ----
  const int s_base = m0 + wr * 64 + ((lane >> 4) << 2);  // + m*16 + r
  const int rem_base = s_base % CYC_ROWS;
  const int d_base = n0 + wc * 64 + l15;                 // + n*16

#pragma unroll
  for (int m = 0; m < 4; ++m) {
#pragma unroll
    for (int r = 0; r < 4; ++r) {
      const int off = m * 16 + r;
      int rem = rem_base + off;
      if (rem >= CYC_ROWS) rem -= CYC_ROWS;
      const unsigned short* trow = tab + (size_t)rem * 1152 + d_base;
      float* orow = outp + (size_t)(s_base + off) * 1152 + d_base;
#pragma unroll
      for (int n = 0; n < 4; ++n)
        orow[n * 16] = acc[m][n][r] + bf2f(trow[n * 16]);
    }
  }
}

extern "C" void kernel_launch(void* const* d_in, const int* in_sizes, int n_in,
                              void* d_out, int out_size, void* d_ws, size_t ws_size,
                              hipStream_t stream) {
  const float* A    = (const float*)d_in[0];  // seq_patches [31744,768]
  const float* W    = (const float*)d_in[1];  // w [1152,768]
  const float* bias = (const float*)d_in[2];  // b [1152]
  const float* pos  = (const float*)d_in[3];  // pos_emb [256,1152]
  unsigned short* Abf = (unsigned short*)d_ws;            // 48.76 MB
  unsigned short* Wbf = Abf + A_ELEMS;                    // +1.77 MB
  unsigned short* tab = Wbf + W_ELEMS;                    // +9.14 MB
  float* outp = (float*)d_out;

  cvt_kernel<<<12336, 256, 0, stream>>>(A, W, Abf);
  tab_kernel<<<2232, 256, 0, stream>>>(pos, bias, tab);
  gemm_kernel<<<2232, 256, 0, stream>>>(Abf, Wbf, tab, outp);
}